// Round 5
// baseline (367.568 us; speedup 1.0000x reference)
//
#include <hip/hip_runtime.h>
#include <math.h>

#define N_ROWS  65536
#define EDIM    256
#define NE      1024
#define BETA    0.25f
#define LAMBDA  0.99f

// margin: worst-case two-sided bf16-filter error bound is 4.8e-3
// (2 * 2^-7 * ||z||*||e|| per side, Cauchy-Schwarz); 8e-3 = verified-passing.
#define MARGIN  8e-3f
#define QCAP    2048

// ---------------- ws layout (float units) ----------------
// [0]        loss accumulator
// [64]       e_sq[1024]       (numpy-exact fp32 row sums of emb*emb)
// [67584]    b_frag           (bf16 emb in MFMA fragment order, 512 KB)
// [198656]   sorted[65536]    (int; row ids grouped by code)
// [264192]   idx[65536] (int)
// [329728]   counts[1024]     (float, for final_kernel)
// [330752]   cnt_i[1024]      (int histogram — zeroed in prep_b, filled in argmin)
// [331776]   offs_i[1024]     (int exclusive prefix)
// [332800]   cursor_i[1024]   (int scatter cursors)

// out layout (float units): loss, z_q_st, idx, perplexity, N_t, m_t
#define O_ZQ   1
#define O_IDX  16777217
#define O_PERP 16842753
#define O_NT   16842754
#define O_MT   16843778

typedef __attribute__((ext_vector_type(8))) short short8;
typedef __attribute__((ext_vector_type(4))) float f32x4;

// RNE float -> bf16 (no NaN in this data)
__device__ __forceinline__ unsigned short f2bf(float f) {
    unsigned u = __float_as_uint(f);
    return (unsigned short)((u + 0x7fffu + ((u >> 16) & 1u)) >> 16);
}

// ---------------------------------------------------------------------------
// prep_b: emb -> bf16 in MFMA B-fragment order; zero loss + histogram.
// Fragment entry (16B = short8) index: (ctg*8 + ks)*64 + lane, holding
// B[k = ks*32 + lg*8 .. +7][col = ctg*16 + l15]  (lane = lg*16 + l15).
__global__ __launch_bounds__(64) void prep_b_kernel(const float* __restrict__ emb,
                                                    unsigned* __restrict__ bfrag_u32,
                                                    float* __restrict__ loss_acc,
                                                    int* __restrict__ cnt) {
    int j = blockIdx.x;          // code id (column)
    int l = threadIdx.x;         // 0..63
    float4 v = ((const float4*)(emb + (size_t)j * EDIM))[l];
    unsigned lo = (unsigned)f2bf(v.x) | ((unsigned)f2bf(v.y) << 16);
    unsigned hi = (unsigned)f2bf(v.z) | ((unsigned)f2bf(v.w) << 16);
    int base = ((((j >> 4) * 8 + (l >> 3)) * 64) + ((l >> 1) & 3) * 16 + (j & 15)) * 4
             + 2 * (l & 1);
    bfrag_u32[base]     = lo;
    bfrag_u32[base + 1] = hi;
    if (l == 0) cnt[j] = 0;
    if (j == 0 && l == 0) *loss_acc = 0.0f;
}

// ---------------------------------------------------------------------------
// sq_kernel (emb): numpy-pairwise-exact fp32 sum of squares — UNCHANGED
// (e_sq enters the cross-candidate exact-d comparison; keep the exact tree).
__global__ __launch_bounds__(256) void sq_kernel(const float* __restrict__ src,
                                                 float* __restrict__ dst) {
    const int tid = threadIdx.x;
    const int grp = tid >> 4;          // 16 rows per block
    const int q   = tid & 15;
    const int row = blockIdx.x * 16 + grp;
    const int h = q >> 3, j = q & 7;
    const float* __restrict__ p = src + (size_t)row * EDIM + h * 128 + j;
    float acc = __fmul_rn(p[0], p[0]);
    #pragma unroll
    for (int t = 1; t < 16; ++t) {
        float v = p[8 * t];
        acc = __fadd_rn(acc, __fmul_rn(v, v));
    }
    acc = __fadd_rn(acc, __shfl_xor(acc, 1));
    acc = __fadd_rn(acc, __shfl_xor(acc, 2));
    acc = __fadd_rn(acc, __shfl_xor(acc, 4));
    acc = __fadd_rn(acc, __shfl_xor(acc, 8));
    if (q == 0) dst[row] = acc;
}

// ---------------------------------------------------------------------------
// argmin_kernel v5: 64 rows/block, 256 threads (4 waves x 16 rows), grid 1024.
// LDS 50.4 KB -> 3 blocks/CU resident (12 waves/CU, was 8): the latency-stall
// fix. Same staged-B pipeline, t-carrying queue + final-min post-filter,
// in-register zsq, fused histogram. Epilogue rewritten fully coalesced
// (1 row per iteration, contiguous dword stores -> L2 line merge).
__global__ __launch_bounds__(256, 3) void argmin_kernel(const float* __restrict__ z,
                                                        const float* __restrict__ emb,
                                                        const float4* __restrict__ bsrc,
                                                        const float* __restrict__ e_sq,
                                                        int* __restrict__ idx_out,
                                                        float* __restrict__ out_zq,
                                                        float* __restrict__ out_idx,
                                                        float* __restrict__ loss_acc,
                                                        int* __restrict__ cnt) {
    __shared__ __align__(16) float4 Bs[2048];    // 32 KB, one B chunk (64 cols x K)
    __shared__ uint2 queue[QCAP];                // 16 KB  (packed rl|col, t-bits)
    __shared__ unsigned long long best_s[64];    // 512 B
    __shared__ int   idx_s[64];
    __shared__ float zsq_s[64];
    __shared__ float rmF_s[64];
    __shared__ int qcnt;

    const int tid  = threadIdx.x;
    const int wid  = tid >> 6, lane = tid & 63;
    const int l15  = lane & 15, lg = lane >> 4;
    const int row0 = blockIdx.x * 64;
    const int rbase = row0 + wid * 16;

    if (tid < 64) best_s[tid] = ~0ull;
    if (tid == 0) qcnt = 0;

    // ---- issue chunk-0 B prefetch first (lands under the A-phase) ----
    float4 st[8];
    #pragma unroll
    for (int i = 0; i < 8; ++i) st[i] = bsrc[tid + 256 * i];

    // ---- A fragments: 16 rows/wave, 8 k-steps, bf16 in regs; zsq on the fly ----
    short8 a[8];
    {
        float zs = 0.f;
        #pragma unroll
        for (int ks = 0; ks < 8; ++ks) {
            const float* zp = z + (size_t)(rbase + l15) * EDIM + ks * 32 + lg * 8;
            float4 f0 = *(const float4*)zp;
            float4 f1 = *(const float4*)(zp + 4);
            zs += f0.x * f0.x + f0.y * f0.y + f0.z * f0.z + f0.w * f0.w
                + f1.x * f1.x + f1.y * f1.y + f1.z * f1.z + f1.w * f1.w;
            union { short8 s; unsigned short u[8]; } pk;
            pk.u[0] = f2bf(f0.x); pk.u[1] = f2bf(f0.y); pk.u[2] = f2bf(f0.z); pk.u[3] = f2bf(f0.w);
            pk.u[4] = f2bf(f1.x); pk.u[5] = f2bf(f1.y); pk.u[6] = f2bf(f1.z); pk.u[7] = f2bf(f1.w);
            a[ks] = pk.s;
        }
        zs += __shfl_xor(zs, 16);        // combine lg groups (row-uniform constant;
        zs += __shfl_xor(zs, 32);        //  cancels in per-row argmin comparison)
        if (lg == 0) zsq_s[wid * 16 + l15] = zs;
    }

    float rm[4];
    #pragma unroll
    for (int r = 0; r < 4; ++r) rm[r] = 1e30f;

    __syncthreads();   // qcnt / best_s init visible

    // ---- main loop: ds_write staged chunk -> barrier -> prefetch next ->
    //      MFMA from LDS -> filter/enqueue(t) -> barrier ----
    for (int ch = 0; ch < 16; ++ch) {
        const int cb = ch * 64;
        #pragma unroll
        for (int i = 0; i < 8; ++i) Bs[tid + 256 * i] = st[i];
        __syncthreads();
        if (ch < 15) {
            #pragma unroll
            for (int i = 0; i < 8; ++i) st[i] = bsrc[(ch + 1) * 2048 + tid + 256 * i];
        }

        float eqs[4];
        #pragma unroll
        for (int ct = 0; ct < 4; ++ct) eqs[ct] = e_sq[cb + ct * 16 + l15];

        f32x4 acc[4];
        #pragma unroll
        for (int ct = 0; ct < 4; ++ct) acc[ct] = (f32x4){0.f, 0.f, 0.f, 0.f};

        const short8* Bv = (const short8*)Bs;
        #pragma unroll
        for (int ks = 0; ks < 8; ++ks) {
            #pragma unroll
            for (int ct = 0; ct < 4; ++ct) {
                short8 b = Bv[(ct * 8 + ks) * 64 + lane];   // conflict-free ds_read_b128
                acc[ct] = __builtin_amdgcn_mfma_f32_16x16x32_bf16(a[ks], b, acc[ct], 0, 0, 0);
            }
        }

        // ---- running row-min (includes this chunk) ----
        #pragma unroll
        for (int r = 0; r < 4; ++r) {
            float m = __fsub_rn(eqs[0], __fmul_rn(2.0f, acc[0][r]));
            #pragma unroll
            for (int ct = 1; ct < 4; ++ct) {
                float t = __fsub_rn(eqs[ct], __fmul_rn(2.0f, acc[ct][r]));
                m = fminf(m, t);
            }
            m = fminf(m, __shfl_xor(m, 1));
            m = fminf(m, __shfl_xor(m, 2));
            m = fminf(m, __shfl_xor(m, 4));
            m = fminf(m, __shfl_xor(m, 8));
            rm[r] = fminf(rm[r], m);
        }

        // ---- enqueue candidates with their t (post-filtered before refine) ----
        #pragma unroll
        for (int ct = 0; ct < 4; ++ct) {
            #pragma unroll
            for (int r = 0; r < 4; ++r) {
                float t = __fsub_rn(eqs[ct], __fmul_rn(2.0f, acc[ct][r]));
                if (t <= rm[r] + MARGIN) {
                    int rl  = wid * 16 + lg * 4 + r;
                    int col = cb + ct * 16 + l15;
                    int s = atomicAdd(&qcnt, 1);
                    if (s < QCAP) queue[s] = make_uint2((rl << 10) | col,
                                                        __float_as_uint(t));
                }
            }
        }
        __syncthreads();   // all waves done reading Bs before next ds_write
    }

    // ---- publish final per-row min for the post-filter ----
    #pragma unroll
    for (int r = 0; r < 4; ++r)
        if (l15 == 0) rmF_s[wid * 16 + lg * 4 + r] = rm[r];
    __syncthreads();

    // ---- cooperative exact refine: 8 lanes per candidate, post-filtered ----
    {
        int nq = qcnt; if (nq > QCAP) nq = QCAP;
        const int g = tid >> 3, q = tid & 7;      // 32 groups
        for (int e = g; e < nq; e += 32) {
            uint2 ent = queue[e];
            int rl = ent.x >> 10, col = ent.x & 1023;
            if (__uint_as_float(ent.y) > rmF_s[rl] + MARGIN) continue;  // ~8x cull
            const float4* zr = (const float4*)(z + (size_t)(row0 + rl) * EDIM);
            const float4* er = (const float4*)(emb + (size_t)col * EDIM);
            float ae = 0.f;
            #pragma unroll
            for (int i = 0; i < 8; ++i) {
                float4 x = zr[q + 8 * i], y = er[q + 8 * i];
                ae = __fmaf_rn(x.x, y.x, ae);
                ae = __fmaf_rn(x.y, y.y, ae);
                ae = __fmaf_rn(x.z, y.z, ae);
                ae = __fmaf_rn(x.w, y.w, ae);
            }
            ae = __fadd_rn(ae, __shfl_xor(ae, 1));
            ae = __fadd_rn(ae, __shfl_xor(ae, 2));
            ae = __fadd_rn(ae, __shfl_xor(ae, 4));
            if (q == 0) {
                float d = __fsub_rn(__fadd_rn(zsq_s[rl], e_sq[col]), __fmul_rn(2.0f, ae));
                unsigned u = __float_as_uint(d);
                u = (u & 0x80000000u) ? ~u : (u | 0x80000000u);   // order-preserving map
                unsigned long long key = ((unsigned long long)u << 32) | (unsigned)col;
                atomicMin(&best_s[rl], key);
            }
        }
    }

    __syncthreads();
    if (tid < 64) {
        unsigned long long k = best_s[tid];
        int id = (int)(k & 0xffffffffull);
        idx_out[row0 + tid] = id;
        out_idx[row0 + tid] = (float)id;
        idx_s[tid] = id;
        atomicAdd(&cnt[id], 1);          // fused histogram
    }
    __syncthreads();

    // ---- z_q store: one row per iteration, all 256 threads contiguous ----
    // (each wave stores 256B of consecutive dwords -> L2 merges full lines;
    //  fixes the 3.4x WRITE_SIZE amplification of the strided-scalar epilogue)
    for (int i = 0; i < 64; ++i) {
        int id = idx_s[i];
        out_zq[(size_t)(row0 + i) * EDIM + tid] = emb[(size_t)id * EDIM + tid];
    }

    // ---- loss: decode the winning refined d per row (wave 0), accumulate ----
    if (wid == 0) {
        unsigned m = (unsigned)(best_s[lane] >> 32);
        unsigned bits = (m & 0x80000000u) ? (m & 0x7fffffffu) : ~m;
        float lp = __uint_as_float(bits);
        #pragma unroll
        for (int mm = 32; mm; mm >>= 1) lp += __shfl_down(lp, mm);
        if (lane == 0) atomicAdd(loss_acc, lp);
    }
}

// ---------------------------------------------------------------------------
// stats via counting sort: scan (offsets, N_t, counts) -> scatter -> msum
__global__ __launch_bounds__(1024) void scan_kernel(const int* __restrict__ cnt,
                                                    const float* __restrict__ N_t,
                                                    float* __restrict__ outN,
                                                    float* __restrict__ counts_f,
                                                    int* __restrict__ offs,
                                                    int* __restrict__ cursor) {
    __shared__ int s[1024];
    const int tid = threadIdx.x;
    int c = cnt[tid];
    s[tid] = c;
    __syncthreads();
    for (int d = 1; d < 1024; d <<= 1) {
        int v = (tid >= d) ? s[tid - d] : 0;
        __syncthreads();
        s[tid] += v;
        __syncthreads();
    }
    int excl = s[tid] - c;
    offs[tid] = excl;
    cursor[tid] = excl;
    counts_f[tid] = (float)c;
    float Nold = N_t[tid];
    outN[tid] = (c > 0) ? Nold * LAMBDA + (float)c * (1.0f - LAMBDA) : Nold;
}

__global__ __launch_bounds__(256) void scatter_kernel(const int* __restrict__ idx,
                                                      int* __restrict__ cursor,
                                                      int* __restrict__ sorted) {
    int i = blockIdx.x * 256 + threadIdx.x;
    int p = atomicAdd(&cursor[idx[i]], 1);
    sorted[p] = i;
}

__global__ __launch_bounds__(512) void msum_kernel(const float* __restrict__ z,
                                                   const int* __restrict__ sorted,
                                                   const int* __restrict__ offs,
                                                   const int* __restrict__ cnt,
                                                   const float* __restrict__ m_t,
                                                   float* __restrict__ outM) {
    const int j = blockIdx.x;
    const int tid = threadIdx.x, w = tid >> 6, lane = tid & 63;
    const int n = cnt[j], start = offs[j];
    float4 acc = make_float4(0.f, 0.f, 0.f, 0.f);
    for (int e = w; e < n; e += 8) {
        float4 v = ((const float4*)(z + (size_t)sorted[start + e] * EDIM))[lane];
        acc.x += v.x; acc.y += v.y; acc.z += v.z; acc.w += v.w;
    }
    __shared__ float red[8 * 256];
    *(float4*)(red + w * 256 + lane * 4) = acc;
    __syncthreads();
    if (tid < 256) {
        float s = 0.f;
        #pragma unroll
        for (int ww = 0; ww < 8; ++ww) s += red[ww * 256 + tid];
        float mold = m_t[(size_t)j * EDIM + tid];
        outM[(size_t)j * EDIM + tid] = (n > 0) ? mold * LAMBDA + s * (1.0f - LAMBDA) : mold;
    }
}

// ---------------------------------------------------------------------------
// finalize — UNCHANGED
__global__ __launch_bounds__(256) void final_kernel(const float* __restrict__ counts,
                                                    const float* __restrict__ loss_acc,
                                                    float* __restrict__ out_loss,
                                                    float* __restrict__ out_perp) {
    const int tid = threadIdx.x, w = tid >> 6, lane = tid & 63;
    float h = 0.f;
    for (int c = tid; c < NE; c += 256) {
        float em = counts[c] * (1.0f / (float)N_ROWS);
        h += em * logf(em + 1e-10f);
    }
    #pragma unroll
    for (int m = 32; m; m >>= 1) h += __shfl_down(h, m);
    __shared__ float red[4];
    if (lane == 0) red[w] = h;
    __syncthreads();
    if (tid == 0) {
        float H = red[0] + red[1] + red[2] + red[3];
        out_perp[0] = expf(-H);
        out_loss[0] = BETA * loss_acc[0] * (1.0f / (float)(N_ROWS * EDIM));
    }
}

// ---------------------------------------------------------------------------
extern "C" void kernel_launch(void* const* d_in, const int* in_sizes, int n_in,
                              void* d_out, int out_size, void* d_ws, size_t ws_size,
                              hipStream_t stream) {
    const float* z   = (const float*)d_in[0];
    const float* emb = (const float*)d_in[1];
    const float* N_t = (const float*)d_in[2];
    const float* m_t = (const float*)d_in[3];
    float* out = (float*)d_out;
    float* ws  = (float*)d_ws;

    float* loss_acc   = ws;
    float* e_sq       = ws + 64;
    unsigned* bfrag_u = (unsigned*)(ws + 67584);
    int*   sorted     = (int*)(ws + 198656);
    int*   idx1       = (int*)(ws + 264192);
    float* counts     = ws + 329728;
    int*   cnt_i      = (int*)(ws + 330752);
    int*   offs_i     = (int*)(ws + 331776);
    int*   cursor_i   = (int*)(ws + 332800);

    prep_b_kernel<<<NE, 64, 0, stream>>>(emb, bfrag_u, loss_acc, cnt_i);
    sq_kernel<<<NE / 16, 256, 0, stream>>>(emb, e_sq);
    argmin_kernel<<<N_ROWS / 64, 256, 0, stream>>>(z, emb, (const float4*)bfrag_u,
                                                   e_sq, idx1,
                                                   out + O_ZQ, out + O_IDX, loss_acc, cnt_i);
    scan_kernel<<<1, 1024, 0, stream>>>(cnt_i, N_t, out + O_NT, counts, offs_i, cursor_i);
    scatter_kernel<<<N_ROWS / 256, 256, 0, stream>>>(idx1, cursor_i, sorted);
    msum_kernel<<<NE, 512, 0, stream>>>(z, sorted, offs_i, cnt_i, m_t, out + O_MT);
    final_kernel<<<1, 256, 0, stream>>>(counts, loss_acc, out, out + O_PERP);
}

// Round 6
// 316.337 us; speedup vs baseline: 1.1620x; 1.1620x over previous
//
#include <hip/hip_runtime.h>
#include <math.h>

#define N_ROWS  65536
#define EDIM    256
#define NE      1024
#define BETA    0.25f
#define LAMBDA  0.99f

// margin: worst-case two-sided bf16-filter error bound is 4.8e-3
// (2 * 2^-7 * ||z||*||e|| per side, Cauchy-Schwarz); 8e-3 = verified-passing.
#define MARGIN  8e-3f
#define QCAP    1024

// ---------------- ws layout (float units) ----------------
// [0]        loss accumulator
// [64]       e_sq[1024]       (numpy-exact fp32 row sums of emb*emb)
// [67584]    b_frag           (bf16 emb in MFMA fragment order, 512 KB)
// [198656]   sorted[65536]    (int; row ids grouped by code)
// [264192]   idx[65536] (int)
// [329728]   counts[1024]     (float, for final_kernel)
// [330752]   cnt_i[1024]      (int histogram — zeroed in prep_b, filled in argmin)
// [331776]   offs_i[1024]     (int exclusive prefix)
// [332800]   cursor_i[1024]   (int scatter cursors)

// out layout (float units): loss, z_q_st, idx, perplexity, N_t, m_t
#define O_ZQ   1
#define O_IDX  16777217
#define O_PERP 16842753
#define O_NT   16842754
#define O_MT   16843778

typedef __attribute__((ext_vector_type(8))) short short8;
typedef __attribute__((ext_vector_type(4))) float f32x4;

// RNE float -> bf16 (no NaN in this data)
__device__ __forceinline__ unsigned short f2bf(float f) {
    unsigned u = __float_as_uint(f);
    return (unsigned short)((u + 0x7fffu + ((u >> 16) & 1u)) >> 16);
}

// ---------------------------------------------------------------------------
// prep_b: emb -> bf16 in MFMA B-fragment order; zero loss + histogram.
// Fragment entry (16B = short8) index: (ctg*8 + ks)*64 + lane, holding
// B[k = ks*32 + lg*8 .. +7][col = ctg*16 + l15]  (lane = lg*16 + l15).
__global__ __launch_bounds__(64) void prep_b_kernel(const float* __restrict__ emb,
                                                    unsigned* __restrict__ bfrag_u32,
                                                    float* __restrict__ loss_acc,
                                                    int* __restrict__ cnt) {
    int j = blockIdx.x;          // code id (column)
    int l = threadIdx.x;         // 0..63
    float4 v = ((const float4*)(emb + (size_t)j * EDIM))[l];
    unsigned lo = (unsigned)f2bf(v.x) | ((unsigned)f2bf(v.y) << 16);
    unsigned hi = (unsigned)f2bf(v.z) | ((unsigned)f2bf(v.w) << 16);
    int base = ((((j >> 4) * 8 + (l >> 3)) * 64) + ((l >> 1) & 3) * 16 + (j & 15)) * 4
             + 2 * (l & 1);
    bfrag_u32[base]     = lo;
    bfrag_u32[base + 1] = hi;
    if (l == 0) cnt[j] = 0;
    if (j == 0 && l == 0) *loss_acc = 0.0f;
}

// ---------------------------------------------------------------------------
// sq_kernel (emb): numpy-pairwise-exact fp32 sum of squares — UNCHANGED
// (e_sq enters the cross-candidate exact-d comparison; keep the exact tree).
__global__ __launch_bounds__(256) void sq_kernel(const float* __restrict__ src,
                                                 float* __restrict__ dst) {
    const int tid = threadIdx.x;
    const int grp = tid >> 4;          // 16 rows per block
    const int q   = tid & 15;
    const int row = blockIdx.x * 16 + grp;
    const int h = q >> 3, j = q & 7;
    const float* __restrict__ p = src + (size_t)row * EDIM + h * 128 + j;
    float acc = __fmul_rn(p[0], p[0]);
    #pragma unroll
    for (int t = 1; t < 16; ++t) {
        float v = p[8 * t];
        acc = __fadd_rn(acc, __fmul_rn(v, v));
    }
    acc = __fadd_rn(acc, __shfl_xor(acc, 1));
    acc = __fadd_rn(acc, __shfl_xor(acc, 2));
    acc = __fadd_rn(acc, __shfl_xor(acc, 4));
    acc = __fadd_rn(acc, __shfl_xor(acc, 8));
    if (q == 0) dst[row] = acc;
}

// ---------------------------------------------------------------------------
// argmin_kernel v6: B staged via global_load_lds (zero staging VGPRs -> no
// scratch spills, the R4/R5 WRITE_SIZE amplifier), 32-col chunks double-
// buffered in LDS (16KB x2), one barrier per chunk (m97 structure: prefetch
// DMA issued before compute, drained by the barrier after a full compute
// phase). 64 rows/block, 256 threads, grid 1024; LDS 41.5KB -> 3 blocks/CU.
// Filter/enqueue/refine/loss logic identical to R4/R5 (bit-exact outputs).
__global__ __launch_bounds__(256, 3) void argmin_kernel(const float* __restrict__ z,
                                                        const float* __restrict__ emb,
                                                        const float4* __restrict__ bsrc,
                                                        const float* __restrict__ e_sq,
                                                        int* __restrict__ idx_out,
                                                        float* __restrict__ out_zq,
                                                        float* __restrict__ out_idx,
                                                        float* __restrict__ loss_acc,
                                                        int* __restrict__ cnt) {
    __shared__ __align__(16) float4 Bs[2][1024];  // 2 x 16 KB (32 cols x 256 k, bf16)
    __shared__ uint2 queue[QCAP];                 // 8 KB  (packed rl|col, t-bits)
    __shared__ unsigned long long best_s[64];     // 512 B
    __shared__ int   idx_s[64];
    __shared__ float zsq_s[64];
    __shared__ float rmF_s[64];
    __shared__ int qcnt;

    const int tid  = threadIdx.x;
    const int wid  = tid >> 6, lane = tid & 63;
    const int l15  = lane & 15, lg = lane >> 4;
    const int row0 = blockIdx.x * 64;
    const int rbase = row0 + wid * 16;

    if (tid < 64) best_s[tid] = ~0ull;
    if (tid == 0) qcnt = 0;

    // ---- stage chunk 0 via async DMA (lands under the A-phase) ----
    // LDS dest is wave-uniform base + lane*16 (HW rule); global src per-lane.
    {
        const char* g = (const char*)bsrc + wid * 4096 + lane * 16;
        char* l = (char*)&Bs[0][0] + wid * 4096;
        #pragma unroll
        for (int i = 0; i < 4; ++i)
            __builtin_amdgcn_global_load_lds(
                (const __attribute__((address_space(1))) unsigned int*)(g + i * 1024),
                (__attribute__((address_space(3))) unsigned int*)(l + i * 1024),
                16, 0, 0);
    }

    // ---- A fragments: 16 rows/wave, 8 k-steps, bf16 in regs; zsq on the fly ----
    short8 a[8];
    {
        float zs = 0.f;
        #pragma unroll
        for (int ks = 0; ks < 8; ++ks) {
            const float* zp = z + (size_t)(rbase + l15) * EDIM + ks * 32 + lg * 8;
            float4 f0 = *(const float4*)zp;
            float4 f1 = *(const float4*)(zp + 4);
            zs += f0.x * f0.x + f0.y * f0.y + f0.z * f0.z + f0.w * f0.w
                + f1.x * f1.x + f1.y * f1.y + f1.z * f1.z + f1.w * f1.w;
            union { short8 s; unsigned short u[8]; } pk;
            pk.u[0] = f2bf(f0.x); pk.u[1] = f2bf(f0.y); pk.u[2] = f2bf(f0.z); pk.u[3] = f2bf(f0.w);
            pk.u[4] = f2bf(f1.x); pk.u[5] = f2bf(f1.y); pk.u[6] = f2bf(f1.z); pk.u[7] = f2bf(f1.w);
            a[ks] = pk.s;
        }
        zs += __shfl_xor(zs, 16);        // combine lg groups (row-uniform constant;
        zs += __shfl_xor(zs, 32);        //  cancels in per-row argmin comparison)
        if (lg == 0) zsq_s[wid * 16 + l15] = zs;
    }

    float rm[4];
    #pragma unroll
    for (int r = 0; r < 4; ++r) rm[r] = 1e30f;

    __syncthreads();   // drains chunk-0 DMA; init + zsq visible

    // ---- main loop: 32 chunks of 32 cols; prefetch DMA -> compute -> barrier ----
    int buf = 0;
    for (int ch = 0; ch < 32; ++ch) {
        const int cb = ch * 32;

        if (ch < 31) {   // issue next-chunk DMA into the other buffer
            const char* g = (const char*)bsrc + (ch + 1) * 16384 + wid * 4096 + lane * 16;
            char* l = (char*)&Bs[buf ^ 1][0] + wid * 4096;
            #pragma unroll
            for (int i = 0; i < 4; ++i)
                __builtin_amdgcn_global_load_lds(
                    (const __attribute__((address_space(1))) unsigned int*)(g + i * 1024),
                    (__attribute__((address_space(3))) unsigned int*)(l + i * 1024),
                    16, 0, 0);
        }

        float eqs[2];
        #pragma unroll
        for (int ct = 0; ct < 2; ++ct) eqs[ct] = e_sq[cb + ct * 16 + l15];

        f32x4 acc[2];
        #pragma unroll
        for (int ct = 0; ct < 2; ++ct) acc[ct] = (f32x4){0.f, 0.f, 0.f, 0.f};

        const short8* Bv = (const short8*)&Bs[buf][0];
        #pragma unroll
        for (int ks = 0; ks < 8; ++ks) {
            #pragma unroll
            for (int ct = 0; ct < 2; ++ct) {
                short8 b = Bv[(ct * 8 + ks) * 64 + lane];   // conflict-free ds_read_b128
                acc[ct] = __builtin_amdgcn_mfma_f32_16x16x32_bf16(a[ks], b, acc[ct], 0, 0, 0);
            }
        }

        // ---- running row-min (includes this chunk) ----
        #pragma unroll
        for (int r = 0; r < 4; ++r) {
            float m0 = __fsub_rn(eqs[0], __fmul_rn(2.0f, acc[0][r]));
            float t1 = __fsub_rn(eqs[1], __fmul_rn(2.0f, acc[1][r]));
            float m = fminf(m0, t1);
            m = fminf(m, __shfl_xor(m, 1));
            m = fminf(m, __shfl_xor(m, 2));
            m = fminf(m, __shfl_xor(m, 4));
            m = fminf(m, __shfl_xor(m, 8));
            rm[r] = fminf(rm[r], m);
        }

        // ---- enqueue candidates with their t (post-filtered before refine) ----
        #pragma unroll
        for (int ct = 0; ct < 2; ++ct) {
            #pragma unroll
            for (int r = 0; r < 4; ++r) {
                float t = __fsub_rn(eqs[ct], __fmul_rn(2.0f, acc[ct][r]));
                if (t <= rm[r] + MARGIN) {
                    int rl  = wid * 16 + lg * 4 + r;
                    int col = cb + ct * 16 + l15;
                    int s = atomicAdd(&qcnt, 1);
                    if (s < QCAP) queue[s] = make_uint2((rl << 10) | col,
                                                        __float_as_uint(t));
                }
            }
        }

        __syncthreads();   // readers done + next-chunk DMA drained
        buf ^= 1;
    }

    // ---- publish final per-row min for the post-filter ----
    #pragma unroll
    for (int r = 0; r < 4; ++r)
        if (l15 == 0) rmF_s[wid * 16 + lg * 4 + r] = rm[r];
    __syncthreads();

    // ---- cooperative exact refine: 8 lanes per candidate, post-filtered ----
    {
        int nq = qcnt; if (nq > QCAP) nq = QCAP;
        const int g = tid >> 3, q = tid & 7;      // 32 groups
        for (int e = g; e < nq; e += 32) {
            uint2 ent = queue[e];
            int rl = ent.x >> 10, col = ent.x & 1023;
            if (__uint_as_float(ent.y) > rmF_s[rl] + MARGIN) continue;  // ~8x cull
            const float4* zr = (const float4*)(z + (size_t)(row0 + rl) * EDIM);
            const float4* er = (const float4*)(emb + (size_t)col * EDIM);
            float ae = 0.f;
            #pragma unroll
            for (int i = 0; i < 8; ++i) {
                float4 x = zr[q + 8 * i], y = er[q + 8 * i];
                ae = __fmaf_rn(x.x, y.x, ae);
                ae = __fmaf_rn(x.y, y.y, ae);
                ae = __fmaf_rn(x.z, y.z, ae);
                ae = __fmaf_rn(x.w, y.w, ae);
            }
            ae = __fadd_rn(ae, __shfl_xor(ae, 1));
            ae = __fadd_rn(ae, __shfl_xor(ae, 2));
            ae = __fadd_rn(ae, __shfl_xor(ae, 4));
            if (q == 0) {
                float d = __fsub_rn(__fadd_rn(zsq_s[rl], e_sq[col]), __fmul_rn(2.0f, ae));
                unsigned u = __float_as_uint(d);
                u = (u & 0x80000000u) ? ~u : (u | 0x80000000u);   // order-preserving map
                unsigned long long key = ((unsigned long long)u << 32) | (unsigned)col;
                atomicMin(&best_s[rl], key);
            }
        }
    }

    __syncthreads();
    if (tid < 64) {
        unsigned long long k = best_s[tid];
        int id = (int)(k & 0xffffffffull);
        idx_out[row0 + tid] = id;
        out_idx[row0 + tid] = (float)id;
        idx_s[tid] = id;
        atomicAdd(&cnt[id], 1);          // fused histogram
    }
    __syncthreads();

    // ---- z_q gather + store: one row per wave per iter (R3-proven pattern:
    //      64 lanes x 16B scalar stores = 1KB contiguous per wave) ----
    const float4* e4 = (const float4*)emb;
    for (int i = 0; i < 16; ++i) {
        int flat = tid + i * 256;
        int r = flat >> 6, c4 = flat & 63;
        int id = idx_s[r];
        float4 e = e4[(size_t)id * 64 + c4];
        float* o = out_zq + (size_t)(row0 + r) * EDIM + c4 * 4;  // base odd-float: scalar stores
        o[0] = e.x; o[1] = e.y; o[2] = e.z; o[3] = e.w;
    }

    // ---- loss: decode the winning refined d per row (wave 0), accumulate ----
    if (wid == 0) {
        unsigned m = (unsigned)(best_s[lane] >> 32);
        unsigned bits = (m & 0x80000000u) ? (m & 0x7fffffffu) : ~m;
        float lp = __uint_as_float(bits);
        #pragma unroll
        for (int mm = 32; mm; mm >>= 1) lp += __shfl_down(lp, mm);
        if (lane == 0) atomicAdd(loss_acc, lp);
    }
}

// ---------------------------------------------------------------------------
// stats via counting sort: scan (offsets, N_t, counts) -> scatter -> msum
__global__ __launch_bounds__(1024) void scan_kernel(const int* __restrict__ cnt,
                                                    const float* __restrict__ N_t,
                                                    float* __restrict__ outN,
                                                    float* __restrict__ counts_f,
                                                    int* __restrict__ offs,
                                                    int* __restrict__ cursor) {
    __shared__ int s[1024];
    const int tid = threadIdx.x;
    int c = cnt[tid];
    s[tid] = c;
    __syncthreads();
    for (int d = 1; d < 1024; d <<= 1) {
        int v = (tid >= d) ? s[tid - d] : 0;
        __syncthreads();
        s[tid] += v;
        __syncthreads();
    }
    int excl = s[tid] - c;
    offs[tid] = excl;
    cursor[tid] = excl;
    counts_f[tid] = (float)c;
    float Nold = N_t[tid];
    outN[tid] = (c > 0) ? Nold * LAMBDA + (float)c * (1.0f - LAMBDA) : Nold;
}

__global__ __launch_bounds__(256) void scatter_kernel(const int* __restrict__ idx,
                                                      int* __restrict__ cursor,
                                                      int* __restrict__ sorted) {
    int i = blockIdx.x * 256 + threadIdx.x;
    int p = atomicAdd(&cursor[idx[i]], 1);
    sorted[p] = i;
}

__global__ __launch_bounds__(512) void msum_kernel(const float* __restrict__ z,
                                                   const int* __restrict__ sorted,
                                                   const int* __restrict__ offs,
                                                   const int* __restrict__ cnt,
                                                   const float* __restrict__ m_t,
                                                   float* __restrict__ outM) {
    const int j = blockIdx.x;
    const int tid = threadIdx.x, w = tid >> 6, lane = tid & 63;
    const int n = cnt[j], start = offs[j];
    float4 acc = make_float4(0.f, 0.f, 0.f, 0.f);
    for (int e = w; e < n; e += 8) {
        float4 v = ((const float4*)(z + (size_t)sorted[start + e] * EDIM))[lane];
        acc.x += v.x; acc.y += v.y; acc.z += v.z; acc.w += v.w;
    }
    __shared__ float red[8 * 256];
    *(float4*)(red + w * 256 + lane * 4) = acc;
    __syncthreads();
    if (tid < 256) {
        float s = 0.f;
        #pragma unroll
        for (int ww = 0; ww < 8; ++ww) s += red[ww * 256 + tid];
        float mold = m_t[(size_t)j * EDIM + tid];
        outM[(size_t)j * EDIM + tid] = (n > 0) ? mold * LAMBDA + s * (1.0f - LAMBDA) : mold;
    }
}

// ---------------------------------------------------------------------------
// finalize — UNCHANGED
__global__ __launch_bounds__(256) void final_kernel(const float* __restrict__ counts,
                                                    const float* __restrict__ loss_acc,
                                                    float* __restrict__ out_loss,
                                                    float* __restrict__ out_perp) {
    const int tid = threadIdx.x, w = tid >> 6, lane = tid & 63;
    float h = 0.f;
    for (int c = tid; c < NE; c += 256) {
        float em = counts[c] * (1.0f / (float)N_ROWS);
        h += em * logf(em + 1e-10f);
    }
    #pragma unroll
    for (int m = 32; m; m >>= 1) h += __shfl_down(h, m);
    __shared__ float red[4];
    if (lane == 0) red[w] = h;
    __syncthreads();
    if (tid == 0) {
        float H = red[0] + red[1] + red[2] + red[3];
        out_perp[0] = expf(-H);
        out_loss[0] = BETA * loss_acc[0] * (1.0f / (float)(N_ROWS * EDIM));
    }
}

// ---------------------------------------------------------------------------
extern "C" void kernel_launch(void* const* d_in, const int* in_sizes, int n_in,
                              void* d_out, int out_size, void* d_ws, size_t ws_size,
                              hipStream_t stream) {
    const float* z   = (const float*)d_in[0];
    const float* emb = (const float*)d_in[1];
    const float* N_t = (const float*)d_in[2];
    const float* m_t = (const float*)d_in[3];
    float* out = (float*)d_out;
    float* ws  = (float*)d_ws;

    float* loss_acc   = ws;
    float* e_sq       = ws + 64;
    unsigned* bfrag_u = (unsigned*)(ws + 67584);
    int*   sorted     = (int*)(ws + 198656);
    int*   idx1       = (int*)(ws + 264192);
    float* counts     = ws + 329728;
    int*   cnt_i      = (int*)(ws + 330752);
    int*   offs_i     = (int*)(ws + 331776);
    int*   cursor_i   = (int*)(ws + 332800);

    prep_b_kernel<<<NE, 64, 0, stream>>>(emb, bfrag_u, loss_acc, cnt_i);
    sq_kernel<<<NE / 16, 256, 0, stream>>>(emb, e_sq);
    argmin_kernel<<<N_ROWS / 64, 256, 0, stream>>>(z, emb, (const float4*)bfrag_u,
                                                   e_sq, idx1,
                                                   out + O_ZQ, out + O_IDX, loss_acc, cnt_i);
    scan_kernel<<<1, 1024, 0, stream>>>(cnt_i, N_t, out + O_NT, counts, offs_i, cursor_i);
    scatter_kernel<<<N_ROWS / 256, 256, 0, stream>>>(idx1, cursor_i, sorted);
    msum_kernel<<<NE, 512, 0, stream>>>(z, sorted, offs_i, cnt_i, m_t, out + O_MT);
    final_kernel<<<1, 256, 0, stream>>>(counts, loss_acc, out, out + O_PERP);
}